// Round 1
// baseline (1788.613 us; speedup 1.0000x reference)
//
#include <hip/hip_runtime.h>
#include <cstdint>
#include <cfloat>

// ---------------------------------------------------------------------------
// SimpleVQVAEEncoder, round 3: table-driven staging + double-buffered LDS.
//  - k -> (input offset, footprint index r) precomputed in prep_kernel,
//    read wave-uniformly via s_load; per-pixel validity is a 64-bit bitmap
//    built once per thread (KH*KW <= 64 for all three convs).
//  - one __syncthreads per K-step (ping-pong LDS), global loads issued
//    before the FMA block so latency hides under compute.
//  - conv3 split 4-way over K for occupancy (338 -> 1352 blocks); partials
//    reduced (with bias) inside vq_kernel. Partial buffer aliases z1.
// ---------------------------------------------------------------------------

constexpr int B_    = 128;
constexpr int HW3   = 169;
constexpr int NPIXT = B_ * HW3;        // 21632
constexpr int NEMB  = 512;
constexpr int EMB   = 64;
constexpr int KS3   = 4;               // conv3 K-split factor

// fused prepass: weight transpose [OC][K] -> [K][OC] and k-table build.
// tab[k] = (ic*IH*IW + ky*IW + kx) << 6 | (ky*KW + kx)   (r < 64 always)
__global__ __launch_bounds__(256) void prep_kernel(
    const float* __restrict__ w, float* __restrict__ wt, int* __restrict__ tab,
    int OC, int K, int KH, int KW, int IH, int IW)
{
    int idx = blockIdx.x * 256 + threadIdx.x;
    if (idx < K) {
        int khw = KH * KW;
        int ic = idx / khw, r = idx - ic * khw;
        int ky = r / KW, kx = r - ky * KW;
        tab[idx] = ((ic * IH * IW + ky * IW + kx) << 6) | r;
    }
    if (idx >= OC * K) return;
    int oc = idx / K, k = idx - oc * K;
    wt[(size_t)k * OC + oc] = w[idx];
}

template<int IC, int OC, int KH, int KW, int IH, int IW, int OH, int OW,
         int STRIDE, int PAD, bool RELU, bool TRANSOUT, bool BIAS, int KSPLIT>
__global__ __launch_bounds__(512) void conv_sgemm(
    const float* __restrict__ in, const float* __restrict__ wt,   // wt: [K][OC]
    const float* __restrict__ bias, const int* __restrict__ ktab,
    float* __restrict__ out)
{
    constexpr int K    = IC * KH * KW;
    constexpr int KSEG = K / KSPLIT;
    constexpr int BK   = 64;
    constexpr int NIT  = KSEG / BK;
    constexpr int NOC  = OC / 8;       // accs per thread
    constexpr int HWo  = OH * OW;
    // footprint always in-bounds (conv3): skip all validity machinery
    constexpr bool NOMASK = (PAD == 0) && ((OH - 1) * STRIDE + KH <= IH)
                                       && ((OW - 1) * STRIDE + KW <= IW);

    __shared__ float As[2][BK][64];    // 32 KB, b32 access: 2-way = free

    const int tid  = threadIdx.x;
    const int lane = tid & 63;
    const int wv   = __builtin_amdgcn_readfirstlane(tid >> 6);  // uniform
    const int oc0  = wv * NOC;

    const int bid     = blockIdx.x;
    const int ks      = bid % KSPLIT;
    const int pixbase = (bid / KSPLIT) * 64;
    const int kbeg    = ks * KSEG;

    // per-pixel decomposition, hoisted out of the K-loop (once per thread)
    const int pix = pixbase + lane;
    const int n   = pix / HWo;
    const int hw  = pix - n * HWo;
    const int oy  = hw / OW;
    const int ox  = hw - oy * OW;
    const long base = (long)n * (IC * IH * IW)
                    + (long)(oy * STRIDE - PAD) * IW + (ox * STRIDE - PAD);

    // validity bitmap over footprint index r = ky*KW + kx (KH*KW <= 64)
    unsigned long long vmask = 0;
    if constexpr (!NOMASK) {
        const int iy0 = oy * STRIDE - PAD, ix0 = ox * STRIDE - PAD;
        unsigned long long colm = 0;
#pragma unroll
        for (int kx = 0; kx < KW; kx++)
            if ((unsigned)(ix0 + kx) < (unsigned)IW) colm |= 1ull << kx;
#pragma unroll
        for (int ky = 0; ky < KH; ky++)
            if ((unsigned)(iy0 + ky) < (unsigned)IH) vmask |= colm << (ky * KW);
    }

    float rg[8];                                   // staged values in flight
    auto stage_load = [&](int k0) {                // issue global loads
#pragma unroll
        for (int i = 0; i < 8; i++) {
            int k  = k0 + i * 8 + wv;              // wave-uniform -> s_load
            int tv = ktab[k];
            int off = tv >> 6;
            if constexpr (NOMASK) {
                rg[i] = in[base + off];
            } else {
                int r   = tv & 63;                 // SALU unpack
                bool ok = (vmask >> r) & 1ull;     // v_lshrrev_b64 + and
                long a  = ok ? (base + off) : 0;
                float v = in[a];
                rg[i]   = ok ? v : 0.f;
            }
        }
    };
    auto stage_write = [&](int buf) {              // regs -> LDS (after vmcnt)
#pragma unroll
        for (int i = 0; i < 8; i++)
            As[buf][i * 8 + wv][lane] = rg[i];
    };

    float acc[NOC];
#pragma unroll
    for (int j = 0; j < NOC; j++) acc[j] = 0.f;

    // prologue
    stage_load(kbeg);
    stage_write(0);
    __syncthreads();

#pragma unroll 1
    for (int t = 0; t < NIT; t++) {
        if (t + 1 < NIT) stage_load(kbeg + (t + 1) * BK);   // hide under FMAs
        const float* bp = wt + (size_t)(kbeg + t * BK) * OC + oc0; // uniform
        const float* as = &As[t & 1][0][0];
#pragma unroll
        for (int kk = 0; kk < BK; kk++) {
            float a = as[kk * 64 + lane];                  // ds_read_b32
#pragma unroll
            for (int j = 0; j < NOC; j++)
                acc[j] = fmaf(a, bp[kk * OC + j], acc[j]); // v_fmac(s,v)
        }
        if (t + 1 < NIT) {
            stage_write((t + 1) & 1);      // writes other buffer: no WAR race
            __syncthreads();               // single barrier per K-step
        }
    }

    // epilogue: bias (+relu), store
#pragma unroll
    for (int j = 0; j < NOC; j++) {
        int oc  = oc0 + j;
        float v = acc[j];
        if (BIAS) v += bias[oc];
        if (RELU) v = fmaxf(v, 0.f);
        if (TRANSOUT) out[((size_t)(ks * OC + oc)) * NPIXT + pix] = v;  // [ks][oc][pix]
        else          out[((size_t)(n * OC + oc)) * HWo + hw] = v;      // NCHW
    }
}

// ---------------------------------------------------------------------------
// VQ: per pixel argmin over 512 codes. z arrives as KS3 K-partials
// [KS3][64][21632] (coalesced); bias folded in here. Codebook reads uniform.
// ---------------------------------------------------------------------------
__global__ __launch_bounds__(256) void vq_kernel(
    const float* __restrict__ zp,           // [KS3][64][21632]
    const float* __restrict__ b3,           // [64]
    const float* __restrict__ cb,           // [512][64]
    unsigned long long* __restrict__ best)  // [21632], preset to ~0
{
    const int tid  = threadIdx.x;
    const int lane = tid & 63;
    const int wv   = tid >> 6;
    const int pg   = blockIdx.x >> 1;
    const int half = blockIdx.x & 1;
    const int p    = pg * 64 + lane;        // 338*64 == 21632 exactly

    __shared__ float c2s[256];
    {
        int code = half * 256 + tid;
        const float* c = cb + (size_t)code * EMB;
        float s = 0.f;
#pragma unroll
        for (int j = 0; j < EMB; j += 4) {
            float4 v = *(const float4*)(c + j);
            s = fmaf(v.x, v.x, s); s = fmaf(v.y, v.y, s);
            s = fmaf(v.z, v.z, s); s = fmaf(v.w, v.w, s);
        }
        c2s[tid] = s;
    }
    __syncthreads();

    float zr[EMB];
    float zz = 0.f;
#pragma unroll
    for (int j = 0; j < EMB; j++) {
        float v = b3[j];
#pragma unroll
        for (int s = 0; s < KS3; s++)
            v += zp[((size_t)(s * EMB + j)) * NPIXT + p];
        zr[j] = v;
        zz = fmaf(v, v, zz);
    }

    float bestScore = FLT_MAX;
    int   bestIdx   = 0x7fffffff;
    const int base = half * 256 + wv * 64;
    for (int ci = 0; ci < 64; ci++) {
        int code = __builtin_amdgcn_readfirstlane(base + ci);
        const float* c = cb + (size_t)code * EMB;
        float dot = 0.f;
#pragma unroll
        for (int j = 0; j < EMB; j++) dot = fmaf(zr[j], c[j], dot);
        float score = fmaf(-2.f, dot, zz) + c2s[code - half * 256];
        if (score < bestScore) { bestScore = score; bestIdx = code; }
    }

    unsigned u = __float_as_uint(bestScore);
    u = (bestScore < 0.f) ? ~u : (u | 0x80000000u);
    unsigned long long pk = ((unsigned long long)u << 32) | (unsigned)bestIdx;
    atomicMin(&best[p], pk);
}

__global__ __launch_bounds__(256) void onehot_kernel(
    const unsigned long long* __restrict__ best, float* __restrict__ out)
{
    int p = blockIdx.x * 256 + threadIdx.x;
    if (p >= NPIXT) return;
    int code = (int)(unsigned)(best[p] & 0xffffffffu);
    int b  = p / HW3;
    int hw = p - b * HW3;
    out[((size_t)b * NEMB + code) * HW3 + hw] = 1.0f;
}

extern "C" void kernel_launch(void* const* d_in, const int* in_sizes, int n_in,
                              void* d_out, int out_size, void* d_ws, size_t ws_size,
                              hipStream_t stream) {
    const float* x  = (const float*)d_in[0];
    const float* w1 = (const float*)d_in[1];
    const float* b1 = (const float*)d_in[2];
    const float* w2 = (const float*)d_in[3];
    const float* b2 = (const float*)d_in[4];
    const float* w3 = (const float*)d_in[5];
    const float* b3 = (const float*)d_in[6];
    const float* cb = (const float*)d_in[7];
    float* out = (float*)d_out;

    float* z1  = (float*)d_ws;                            // 128*64*48*48 = 75.5 MB
    float* z2  = z1 + (size_t)128 * 64 * 48 * 48;         // 128*128*16*16 = 16.8 MB
    float* z3p = z1;            // conv3 partials [KS3][64][21632] = 22.1 MB, aliases
                                // z1 (dead after conv2; fits in its 75.5 MB)
    unsigned long long* best = (unsigned long long*)(z2 + (size_t)128 * 128 * 16 * 16);
    float* w1t = (float*)(best + NPIXT);                  // [192][64]
    float* w2t = w1t + 192 * 64;                          // [2304][128]
    float* w3t = w2t + 2304 * 128;                        // [2048][64]
    int* kt1 = (int*)(w3t + 2048 * 64);                   // [192]
    int* kt2 = kt1 + 192;                                 // [2304]
    int* kt3 = kt2 + 2304;                                // [2048]

    hipMemsetAsync(out, 0, (size_t)out_size * sizeof(float), stream);
    hipMemsetAsync(best, 0xFF, (size_t)NPIXT * sizeof(unsigned long long), stream);

    prep_kernel<<<(64 * 192 + 255) / 256, 256, 0, stream>>>(w1, w1t, kt1, 64, 192, 8, 8, 192, 192);
    prep_kernel<<<(128 * 2304 + 255) / 256, 256, 0, stream>>>(w2, w2t, kt2, 128, 2304, 6, 6, 48, 48);
    prep_kernel<<<(64 * 2048 + 255) / 256, 256, 0, stream>>>(w3, w3t, kt3, 64, 2048, 4, 4, 16, 16);

    // conv1: M = 294912 pixels -> 4608 blocks, K=192
    conv_sgemm<3, 64, 8, 8, 192, 192, 48, 48, 4, 2, true, false, true, 1>
        <<<294912 / 64, 512, 0, stream>>>(x, w1t, b1, kt1, z1);
    // conv2: M = 32768 pixels -> 512 blocks, K=2304 (the big one)
    conv_sgemm<64, 128, 6, 6, 48, 48, 16, 16, 3, 2, true, false, true, 1>
        <<<32768 / 64, 512, 0, stream>>>(z1, w2t, b2, kt2, z2);
    // conv3: K=2048 split 4-way -> 1352 blocks; partials, no bias (folded in VQ)
    conv_sgemm<128, 64, 4, 4, 16, 16, 13, 13, 1, 0, false, true, false, KS3>
        <<<(NPIXT / 64) * KS3, 512, 0, stream>>>(z2, w3t, b3, kt3, z3p);

    vq_kernel<<<338 * 2, 256, 0, stream>>>(z3p, b3, cb, best);
    onehot_kernel<<<(NPIXT + 255) / 256, 256, 0, stream>>>(best, out);
}

// Round 2
// 902.948 us; speedup vs baseline: 1.9809x; 1.9809x over previous
//
#include <hip/hip_runtime.h>
#include <cstdint>
#include <cfloat>

// ---------------------------------------------------------------------------
// SimpleVQVAEEncoder, round 4: revert to the proven R0 "scalar-broadcast"
// implicit-GEMM template (756 µs), plus ONE mechanical change: OCSPLIT.
// Each block computes OC/OCSPLIT output channels so grid-limited convs
// (conv2: 512 blocks = 2/CU, conv3: 338 = 1.3/CU) get 2x block-level
// overlap across barrier/latency stalls. Identical math, no partials,
// no extra workspace. Everything else byte-identical to R0.
// ---------------------------------------------------------------------------

constexpr int B_    = 128;
constexpr int HW3   = 169;
constexpr int NPIXT = B_ * HW3;        // 21632
constexpr int NEMB  = 512;
constexpr int EMB   = 64;

// transpose weights [OC][K] -> [K][OC] (tiny prepass)
__global__ __launch_bounds__(256) void wtrans_kernel(
    const float* __restrict__ w, float* __restrict__ wt, int OC, int K)
{
    int idx = blockIdx.x * 256 + threadIdx.x;
    if (idx >= OC * K) return;
    int oc = idx / K, k = idx - oc * K;
    wt[(size_t)k * OC + oc] = w[idx];
}

template<int IC, int OC, int KH, int KW, int IH, int IW, int OH, int OW,
         int STRIDE, int PAD, bool RELU, bool TRANSOUT, int OCSPLIT>
__global__ __launch_bounds__(512) void conv_sgemm(
    const float* __restrict__ in, const float* __restrict__ wt,   // wt: [K][OC]
    const float* __restrict__ bias, float* __restrict__ out)
{
    constexpr int K   = IC * KH * KW;
    constexpr int BK  = 32;
    constexpr int NOC = OC / OCSPLIT / 8;  // accs per thread
    constexpr int HWo = OH * OW;

    __shared__ float As[BK][64];       // b32 reads: bank = lane%32, 2-way = free

    const int tid  = threadIdx.x;
    const int lane = tid & 63;
    const int wv   = __builtin_amdgcn_readfirstlane(tid >> 6);  // force uniform
    const int osp  = blockIdx.x % OCSPLIT;
    const int oc0  = osp * (OC / OCSPLIT) + wv * NOC;
    const int pixbase = (blockIdx.x / OCSPLIT) * 64;

    float acc[NOC];
#pragma unroll
    for (int j = 0; j < NOC; j++) acc[j] = 0.f;

    for (int k0 = 0; k0 < K; k0 += BK) {
        __syncthreads();               // previous iter's reads done
#pragma unroll
        for (int i = 0; i < (BK * 64) / 512; i++) {      // 4 elems/thread
            int idx = i * 512 + tid;
            int p  = idx & 63;
            int kk = idx >> 6;
            int k  = k0 + kk;
            int ic = k / (KH * KW);
            int r  = k - ic * (KH * KW);
            int ky = r / KW;
            int kx = r - ky * KW;
            int pix = pixbase + p;
            int n  = pix / HWo;
            int hw = pix - n * HWo;
            int oy = hw / OW;
            int ox = hw - oy * OW;
            int iy = oy * STRIDE - PAD + ky;
            int ix = ox * STRIDE - PAD + kx;
            float v = 0.f;
            if (iy >= 0 && iy < IH && ix >= 0 && ix < IW)
                v = in[((size_t)(n * IC + ic) * IH + iy) * IW + ix];
            As[kk][p] = v;
        }
        __syncthreads();

        const float* bp = wt + (size_t)k0 * OC + oc0;    // wave-uniform address
#pragma unroll
        for (int kk = 0; kk < BK; kk++) {
            float a = As[kk][lane];
#pragma unroll
            for (int j = 0; j < NOC; j++)
                acc[j] = fmaf(a, bp[kk * OC + j], acc[j]);   // s_load + v_fmac(s,v)
        }
    }

    // epilogue: bias (+relu), store
    int pix = pixbase + lane;
    int n   = pix / HWo;
    int hw  = pix - n * HWo;
#pragma unroll
    for (int j = 0; j < NOC; j++) {
        int oc  = oc0 + j;
        float v = acc[j] + bias[oc];
        if (RELU) v = fmaxf(v, 0.f);
        if (TRANSOUT) out[(size_t)oc * NPIXT + pix] = v;                 // z3t[oc][pix]
        else          out[((size_t)(n * OC + oc)) * HWo + hw] = v;       // NCHW
    }
}

// ---------------------------------------------------------------------------
// VQ: per pixel argmin over 512 codes of |z|^2 - 2 z.c + |c|^2.
// z transposed [64][21632] -> coalesced loads. Codebook reads wave-uniform.
// ---------------------------------------------------------------------------
__global__ __launch_bounds__(256) void vq_kernel(
    const float* __restrict__ zt,           // [64][21632]
    const float* __restrict__ cb,           // [512][64]
    unsigned long long* __restrict__ best)  // [21632], preset to ~0
{
    const int tid  = threadIdx.x;
    const int lane = tid & 63;
    const int wv   = tid >> 6;
    const int pg   = blockIdx.x >> 1;
    const int half = blockIdx.x & 1;
    const int p    = pg * 64 + lane;        // 338*64 == 21632 exactly

    __shared__ float c2s[256];
    {
        int code = half * 256 + tid;
        const float* c = cb + (size_t)code * EMB;
        float s = 0.f;
#pragma unroll
        for (int j = 0; j < EMB; j += 4) {
            float4 v = *(const float4*)(c + j);
            s = fmaf(v.x, v.x, s); s = fmaf(v.y, v.y, s);
            s = fmaf(v.z, v.z, s); s = fmaf(v.w, v.w, s);
        }
        c2s[tid] = s;
    }
    __syncthreads();

    float zr[EMB];
    float zz = 0.f;
#pragma unroll
    for (int j = 0; j < EMB; j++) {
        float v = zt[(size_t)j * NPIXT + p];
        zr[j] = v;
        zz = fmaf(v, v, zz);
    }

    float bestScore = FLT_MAX;
    int   bestIdx   = 0x7fffffff;
    const int base = half * 256 + wv * 64;
    for (int ci = 0; ci < 64; ci++) {
        int code = __builtin_amdgcn_readfirstlane(base + ci);
        const float* c = cb + (size_t)code * EMB;
        float dot = 0.f;
#pragma unroll
        for (int j = 0; j < EMB; j++) dot = fmaf(zr[j], c[j], dot);
        float score = fmaf(-2.f, dot, zz) + c2s[code - half * 256];
        if (score < bestScore) { bestScore = score; bestIdx = code; }
    }

    unsigned u = __float_as_uint(bestScore);
    u = (bestScore < 0.f) ? ~u : (u | 0x80000000u);
    unsigned long long pk = ((unsigned long long)u << 32) | (unsigned)bestIdx;
    atomicMin(&best[p], pk);
}

__global__ __launch_bounds__(256) void onehot_kernel(
    const unsigned long long* __restrict__ best, float* __restrict__ out)
{
    int p = blockIdx.x * 256 + threadIdx.x;
    if (p >= NPIXT) return;
    int code = (int)(unsigned)(best[p] & 0xffffffffu);
    int b  = p / HW3;
    int hw = p - b * HW3;
    out[((size_t)b * NEMB + code) * HW3 + hw] = 1.0f;
}

extern "C" void kernel_launch(void* const* d_in, const int* in_sizes, int n_in,
                              void* d_out, int out_size, void* d_ws, size_t ws_size,
                              hipStream_t stream) {
    const float* x  = (const float*)d_in[0];
    const float* w1 = (const float*)d_in[1];
    const float* b1 = (const float*)d_in[2];
    const float* w2 = (const float*)d_in[3];
    const float* b2 = (const float*)d_in[4];
    const float* w3 = (const float*)d_in[5];
    const float* b3 = (const float*)d_in[6];
    const float* cb = (const float*)d_in[7];
    float* out = (float*)d_out;

    float* z1  = (float*)d_ws;                            // 128*64*48*48   = 75.5 MB
    float* z2  = z1 + (size_t)128 * 64 * 48 * 48;         // 128*128*16*16  = 16.8 MB
    float* z3t = z2 + (size_t)128 * 128 * 16 * 16;        // [64][21632]    =  5.5 MB
    unsigned long long* best = (unsigned long long*)(z3t + (size_t)EMB * NPIXT);
    float* w1t = (float*)(best + NPIXT);                  // [192][64]
    float* w2t = w1t + 192 * 64;                          // [2304][128]
    float* w3t = w2t + 2304 * 128;                        // [2048][64]

    hipMemsetAsync(out, 0, (size_t)out_size * sizeof(float), stream);
    hipMemsetAsync(best, 0xFF, (size_t)NPIXT * sizeof(unsigned long long), stream);

    wtrans_kernel<<<(64 * 192 + 255) / 256, 256, 0, stream>>>(w1, w1t, 64, 192);
    wtrans_kernel<<<(128 * 2304 + 255) / 256, 256, 0, stream>>>(w2, w2t, 128, 2304);
    wtrans_kernel<<<(64 * 2048 + 255) / 256, 256, 0, stream>>>(w3, w3t, 64, 2048);

    // conv1: M = 294912 pixels -> 4608 blocks (18/CU, not grid-limited)
    conv_sgemm<3, 64, 8, 8, 192, 192, 48, 48, 4, 2, true, false, 1>
        <<<294912 / 64, 512, 0, stream>>>(x, w1t, b1, z1);
    // conv2: OC-split x2 -> 1024 blocks = 4 blocks/CU (32 waves/CU)
    conv_sgemm<64, 128, 6, 6, 48, 48, 16, 16, 3, 2, true, false, 2>
        <<<(32768 / 64) * 2, 512, 0, stream>>>(z1, w2t, b2, z2);
    // conv3: OC-split x2 -> 676 blocks = 2.6 blocks/CU, transposed output
    conv_sgemm<128, 64, 4, 4, 16, 16, 13, 13, 1, 0, false, true, 2>
        <<<(NPIXT / 64) * 2, 512, 0, stream>>>(z2, w3t, b3, z3t);

    vq_kernel<<<338 * 2, 256, 0, stream>>>(z3t, cb, best);
    onehot_kernel<<<(NPIXT + 255) / 256, 256, 0, stream>>>(best, out);
}

// Round 3
// 688.763 us; speedup vs baseline: 2.5968x; 1.3110x over previous
//
#include <hip/hip_runtime.h>
#include <cstdint>
#include <cfloat>

// ---------------------------------------------------------------------------
// SimpleVQVAEEncoder, round 5: R0 "scalar-broadcast" implicit-GEMM base
// (proven 757 µs) with ONE change: cheap staging.
//  - pixel decomposition (n, oy, ox, base ptr) hoisted out of the K-loop
//  - element->thread map so each wave stages rows kk = wv*4+i: the
//    k-decomposition (ic,ky,kx, channel offset) is wave-uniform -> SALU
//  - per staged element: 2 adds + 2 cmps + 1 mad + masked load + ds_write
//    (was ~25 VALU of magic-mul div/mod chains per element per K-step)
// Everything else (BK=32, 2 barriers/K-step, FMA loop, vq, onehot)
// byte-identical to the 757 µs version. conv3 keeps OCSPLIT=2 (R2: neutral,
// raises grid 338->676 = 2.6 blocks/CU).
// ---------------------------------------------------------------------------

constexpr int B_    = 128;
constexpr int HW3   = 169;
constexpr int NPIXT = B_ * HW3;        // 21632
constexpr int NEMB  = 512;
constexpr int EMB   = 64;

// transpose weights [OC][K] -> [K][OC] (tiny prepass)
__global__ __launch_bounds__(256) void wtrans_kernel(
    const float* __restrict__ w, float* __restrict__ wt, int OC, int K)
{
    int idx = blockIdx.x * 256 + threadIdx.x;
    if (idx >= OC * K) return;
    int oc = idx / K, k = idx - oc * K;
    wt[(size_t)k * OC + oc] = w[idx];
}

template<int IC, int OC, int KH, int KW, int IH, int IW, int OH, int OW,
         int STRIDE, int PAD, bool RELU, bool TRANSOUT, int OCSPLIT>
__global__ __launch_bounds__(512) void conv_sgemm(
    const float* __restrict__ in, const float* __restrict__ wt,   // wt: [K][OC]
    const float* __restrict__ bias, float* __restrict__ out)
{
    constexpr int K   = IC * KH * KW;
    constexpr int KHW = KH * KW;
    constexpr int BK  = 32;
    constexpr int NOC = OC / OCSPLIT / 8;  // accs per thread
    constexpr int HWo = OH * OW;

    __shared__ float As[BK][64];       // b32 reads: bank = lane%32, 2-way = free

    const int tid  = threadIdx.x;
    const int lane = tid & 63;
    const int wv   = __builtin_amdgcn_readfirstlane(tid >> 6);  // force uniform
    const int osp  = blockIdx.x % OCSPLIT;
    const int oc0  = osp * (OC / OCSPLIT) + wv * NOC;
    const int pixbase = (blockIdx.x / OCSPLIT) * 64;

    // ---- hoisted pixel decomposition (lane-dependent only, once) ----
    const int pix = pixbase + lane;
    const int n   = pix / HWo;
    const int hw  = pix - n * HWo;
    const int oy  = hw / OW;
    const int ox  = hw - oy * OW;
    const int iyb = oy * STRIDE - PAD;
    const int ixb = ox * STRIDE - PAD;
    const float* inb = in + (size_t)n * (IC * IH * IW);

    float acc[NOC];
#pragma unroll
    for (int j = 0; j < NOC; j++) acc[j] = 0.f;

    for (int k0 = 0; k0 < K; k0 += BK) {
        __syncthreads();               // previous iter's reads done
#pragma unroll
        for (int i = 0; i < BK / 8; i++) {
            int kk = wv * (BK / 8) + i;          // wave-uniform row
            int k  = k0 + kk;                    // uniform
            int ic = k / KHW;                    // uniform -> SALU
            int r  = k - ic * KHW;
            int ky = r / KW;
            int kx = r - ky * KW;
            int iy = iyb + ky;                   // per-lane: 1 add
            int ix = ixb + kx;                   // 1 add
            int off = (ic * IH + iy) * IW + ix;  // mad (ic*IH uniform)
            float v = 0.f;
            if ((unsigned)iy < (unsigned)IH && (unsigned)ix < (unsigned)IW)
                v = inb[off];                    // exec-masked load
            As[kk][lane] = v;
        }
        __syncthreads();

        const float* bp = wt + (size_t)k0 * OC + oc0;    // wave-uniform address
#pragma unroll
        for (int kk = 0; kk < BK; kk++) {
            float a = As[kk][lane];
#pragma unroll
            for (int j = 0; j < NOC; j++)
                acc[j] = fmaf(a, bp[kk * OC + j], acc[j]);   // s_load + v_fmac(s,v)
        }
    }

    // epilogue: bias (+relu), store
#pragma unroll
    for (int j = 0; j < NOC; j++) {
        int oc  = oc0 + j;
        float v = acc[j] + bias[oc];
        if (RELU) v = fmaxf(v, 0.f);
        if (TRANSOUT) out[(size_t)oc * NPIXT + pix] = v;                 // z3t[oc][pix]
        else          out[((size_t)(n * OC + oc)) * HWo + hw] = v;       // NCHW
    }
}

// ---------------------------------------------------------------------------
// VQ: per pixel argmin over 512 codes of |z|^2 - 2 z.c + |c|^2.
// z transposed [64][21632] -> coalesced loads. Codebook reads wave-uniform.
// ---------------------------------------------------------------------------
__global__ __launch_bounds__(256) void vq_kernel(
    const float* __restrict__ zt,           // [64][21632]
    const float* __restrict__ cb,           // [512][64]
    unsigned long long* __restrict__ best)  // [21632], preset to ~0
{
    const int tid  = threadIdx.x;
    const int lane = tid & 63;
    const int wv   = tid >> 6;
    const int pg   = blockIdx.x >> 1;
    const int half = blockIdx.x & 1;
    const int p    = pg * 64 + lane;        // 338*64 == 21632 exactly

    __shared__ float c2s[256];
    {
        int code = half * 256 + tid;
        const float* c = cb + (size_t)code * EMB;
        float s = 0.f;
#pragma unroll
        for (int j = 0; j < EMB; j += 4) {
            float4 v = *(const float4*)(c + j);
            s = fmaf(v.x, v.x, s); s = fmaf(v.y, v.y, s);
            s = fmaf(v.z, v.z, s); s = fmaf(v.w, v.w, s);
        }
        c2s[tid] = s;
    }
    __syncthreads();

    float zr[EMB];
    float zz = 0.f;
#pragma unroll
    for (int j = 0; j < EMB; j++) {
        float v = zt[(size_t)j * NPIXT + p];
        zr[j] = v;
        zz = fmaf(v, v, zz);
    }

    float bestScore = FLT_MAX;
    int   bestIdx   = 0x7fffffff;
    const int base = half * 256 + wv * 64;
    for (int ci = 0; ci < 64; ci++) {
        int code = __builtin_amdgcn_readfirstlane(base + ci);
        const float* c = cb + (size_t)code * EMB;
        float dot = 0.f;
#pragma unroll
        for (int j = 0; j < EMB; j++) dot = fmaf(zr[j], c[j], dot);
        float score = fmaf(-2.f, dot, zz) + c2s[code - half * 256];
        if (score < bestScore) { bestScore = score; bestIdx = code; }
    }

    unsigned u = __float_as_uint(bestScore);
    u = (bestScore < 0.f) ? ~u : (u | 0x80000000u);
    unsigned long long pk = ((unsigned long long)u << 32) | (unsigned)bestIdx;
    atomicMin(&best[p], pk);
}

__global__ __launch_bounds__(256) void onehot_kernel(
    const unsigned long long* __restrict__ best, float* __restrict__ out)
{
    int p = blockIdx.x * 256 + threadIdx.x;
    if (p >= NPIXT) return;
    int code = (int)(unsigned)(best[p] & 0xffffffffu);
    int b  = p / HW3;
    int hw = p - b * HW3;
    out[((size_t)b * NEMB + code) * HW3 + hw] = 1.0f;
}

extern "C" void kernel_launch(void* const* d_in, const int* in_sizes, int n_in,
                              void* d_out, int out_size, void* d_ws, size_t ws_size,
                              hipStream_t stream) {
    const float* x  = (const float*)d_in[0];
    const float* w1 = (const float*)d_in[1];
    const float* b1 = (const float*)d_in[2];
    const float* w2 = (const float*)d_in[3];
    const float* b2 = (const float*)d_in[4];
    const float* w3 = (const float*)d_in[5];
    const float* b3 = (const float*)d_in[6];
    const float* cb = (const float*)d_in[7];
    float* out = (float*)d_out;

    float* z1  = (float*)d_ws;                            // 128*64*48*48   = 75.5 MB
    float* z2  = z1 + (size_t)128 * 64 * 48 * 48;         // 128*128*16*16  = 16.8 MB
    float* z3t = z2 + (size_t)128 * 128 * 16 * 16;        // [64][21632]    =  5.5 MB
    unsigned long long* best = (unsigned long long*)(z3t + (size_t)EMB * NPIXT);
    float* w1t = (float*)(best + NPIXT);                  // [192][64]
    float* w2t = w1t + 192 * 64;                          // [2304][128]
    float* w3t = w2t + 2304 * 128;                        // [2048][64]

    hipMemsetAsync(out, 0, (size_t)out_size * sizeof(float), stream);
    hipMemsetAsync(best, 0xFF, (size_t)NPIXT * sizeof(unsigned long long), stream);

    wtrans_kernel<<<(64 * 192 + 255) / 256, 256, 0, stream>>>(w1, w1t, 64, 192);
    wtrans_kernel<<<(128 * 2304 + 255) / 256, 256, 0, stream>>>(w2, w2t, 128, 2304);
    wtrans_kernel<<<(64 * 2048 + 255) / 256, 256, 0, stream>>>(w3, w3t, 64, 2048);

    // conv1: M = 294912 pixels -> 4608 blocks (18/CU)
    conv_sgemm<3, 64, 8, 8, 192, 192, 48, 48, 4, 2, true, false, 1>
        <<<294912 / 64, 512, 0, stream>>>(x, w1t, b1, z1);
    // conv2: M = 32768 pixels -> 512 blocks, full OC per block
    conv_sgemm<64, 128, 6, 6, 48, 48, 16, 16, 3, 2, true, false, 1>
        <<<32768 / 64, 512, 0, stream>>>(z1, w2t, b2, z2);
    // conv3: OC-split x2 -> 676 blocks = 2.6 blocks/CU, transposed output
    conv_sgemm<128, 64, 4, 4, 16, 16, 13, 13, 1, 0, false, true, 2>
        <<<(NPIXT / 64) * 2, 512, 0, stream>>>(z2, w3t, b3, z3t);

    vq_kernel<<<338 * 2, 256, 0, stream>>>(z3t, cb, best);
    onehot_kernel<<<(NPIXT + 255) / 256, 256, 0, stream>>>(best, out);
}